// Round 1
// baseline (827.958 us; speedup 1.0000x reference)
//
#include <hip/hip_runtime.h>

#define NN 100000
#define NE 1600000
#define INC 128
#define TE 32
#define OC 128
#define NR 8
#define NB 8
#define FT 160
#define KP 168          // padded K stride (bf16 elems): 168*2B rows -> 2-way LDS aliasing only (free)
#define TN 64           // nodes per block
#define NKEY (NN*NR)    // 800000

typedef float f32x4 __attribute__((ext_vector_type(4)));
typedef __bf16 bf16x8 __attribute__((ext_vector_type(8)));

__device__ __forceinline__ unsigned short f2bf(float f) {
    unsigned u = __float_as_uint(f);
    unsigned r = (u + 0x7fffu + ((u >> 16) & 1u)) >> 16;
    return (unsigned short)r;
}

// ---- Wt[ridx][o][k] bf16, ridx 0..7 = relations (comp @ bases), ridx 8 = root_w ----
__global__ void k_wt(const float* __restrict__ comp, const float* __restrict__ bases,
                     const float* __restrict__ rootw, unsigned short* __restrict__ Wt) {
    int idx = blockIdx.x * 256 + threadIdx.x;
    const int tot = 9 * 128 * KP;
    if (idx >= tot) return;
    int ridx = idx / (128 * KP);
    int rem  = idx % (128 * KP);
    int o = rem / KP;
    int k = rem % KP;
    float v = 0.f;
    if (k < FT) {
        if (ridx < NR) {
#pragma unroll
            for (int b = 0; b < NB; b++)
                v += comp[ridx * NB + b] * bases[(b * FT + k) * OC + o];
        } else {
            v = rootw[k * OC + o];
        }
    }
    Wt[idx] = f2bf(v);
}

__global__ void k_count(const int* __restrict__ ei, const int* __restrict__ et,
                        int* __restrict__ cnts) {
    int e = blockIdx.x * 256 + threadIdx.x;
    if (e < NE) {
        int dst = ei[NE + e];
        int t = et[e];
        atomicAdd(&cnts[dst * NR + t], 1);
    }
}

// bucket start offsets via wave-scan + one atomic per wave (order-free grouping)
__global__ void k_starts(const int* __restrict__ cnts, int* __restrict__ starts,
                         int* __restrict__ fillp, int* __restrict__ cursor) {
    int idx = blockIdx.x * 256 + threadIdx.x;
    int lane = threadIdx.x & 63;
    int c = (idx < NKEY) ? cnts[idx] : 0;
    int v = c;
#pragma unroll
    for (int d = 1; d < 64; d <<= 1) {
        int t = __shfl_up(v, d);
        if (lane >= d) v += t;
    }
    int total = __shfl(v, 63);
    int base = 0;
    if (lane == 63) base = atomicAdd(cursor, total);
    base = __shfl(base, 63);
    int st = base + v - c;   // exclusive prefix within wave
    if (idx < NKEY) { starts[idx] = st; fillp[idx] = st; }
}

__global__ void k_fill(const int* __restrict__ ei, const int* __restrict__ et,
                       int* __restrict__ fillp, int* __restrict__ slots) {
    int e = blockIdx.x * 256 + threadIdx.x;
    if (e < NE) {
        int src = ei[e];
        int dst = ei[NE + e];
        int t = et[e];
        int pos = atomicAdd(&fillp[dst * NR + t], 1);
        slots[pos] = src;
    }
}

// ---- fused: root GEMM + per-relation (aggregate mean -> GEMM) + bias + ReLU ----
__global__ __launch_bounds__(256) void k_mega(
    const float* __restrict__ x, const int* __restrict__ ntype,
    const float* __restrict__ emb, const float* __restrict__ bias,
    const unsigned short* __restrict__ Wt, const int* __restrict__ cnts,
    const int* __restrict__ starts, const int* __restrict__ slots,
    float* __restrict__ out) {
    __shared__ unsigned short Wl[128 * KP];   // W^T: [o][k] bf16, 43008 B
    __shared__ unsigned short feat[TN * KP];  // [n][k] bf16, 21504 B  (total 64512 <= 64K)

    const int tid = threadIdx.x;
    const int lane = tid & 63;
    const int wave = tid >> 6;
    const int n0 = blockIdx.x * TN;

    f32x4 acc[8];
#pragma unroll
    for (int t = 0; t < 8; t++) acc[t] = (f32x4){0.f, 0.f, 0.f, 0.f};

    auto stage_w = [&](int ridx) {
        const uint4* s = reinterpret_cast<const uint4*>(Wt + ridx * 128 * KP);
        uint4* d = reinterpret_cast<uint4*>(Wl);
        for (int i = tid; i < (128 * KP) / 8; i += 256) d[i] = s[i];
    };

    auto mfma_pass = [&]() {
        const unsigned short* fA = feat + (wave * 16 + (lane & 15)) * KP + ((lane >> 4) * 8);
        const unsigned short* fB = Wl + (lane & 15) * KP + ((lane >> 4) * 8);
#pragma unroll
        for (int kc = 0; kc < 5; kc++) {
            bf16x8 a = *reinterpret_cast<const bf16x8*>(fA + kc * 32);
#pragma unroll
            for (int t = 0; t < 8; t++) {
                bf16x8 b = *reinterpret_cast<const bf16x8*>(fB + t * 16 * KP + kc * 32);
                acc[t] = __builtin_amdgcn_mfma_f32_16x16x32_bf16(a, b, acc[t], 0, 0, 0);
            }
        }
    };

    // ---------- root pass: feat = concat(x, emb[type]) ----------
    stage_w(8);
    for (int i = tid; i < TN * (FT / 4); i += 256) {
        int nl = i / (FT / 4);
        int f = (i % (FT / 4)) * 4;
        int n = n0 + nl;
        f32x4 v = (f32x4){0.f, 0.f, 0.f, 0.f};
        if (n < NN) {
            if (f < INC) v = *reinterpret_cast<const f32x4*>(x + (size_t)n * INC + f);
            else {
                int tt = ntype[n];
                v = *reinterpret_cast<const f32x4*>(emb + tt * TE + (f - INC));
            }
        }
        unsigned lo = (unsigned)f2bf(v[0]) | ((unsigned)f2bf(v[1]) << 16);
        unsigned hi = (unsigned)f2bf(v[2]) | ((unsigned)f2bf(v[3]) << 16);
        unsigned* p = reinterpret_cast<unsigned*>(feat + nl * KP + f);
        p[0] = lo; p[1] = hi;
    }
    __syncthreads();
    mfma_pass();

    // ---------- relation passes ----------
    for (int r = 0; r < NR; r++) {
        __syncthreads();          // previous mfma done reading LDS
        stage_w(r);
        {   // aggregate mean into feat: 4 threads per node, 40 feats each (fp32 regs)
            int nl = tid >> 2, j = tid & 3;
            int n = n0 + nl;
            float sacc[40];
#pragma unroll
            for (int i = 0; i < 40; i++) sacc[i] = 0.f;
            int cnt = 0;
            if (n < NN) {
                int key = n * NR + r;
                cnt = cnts[key];
                int st = starts[key];
                for (int e = 0; e < cnt; e++) {
                    int src = slots[st + e];
                    const float* xs = x + (size_t)src * INC + j * 40;
                    int tt = (j == 3) ? ntype[src] : 0;
                    const float* es = emb + tt * TE;
#pragma unroll
                    for (int c = 0; c < 10; c++) {
                        int f = j * 40 + c * 4;
                        f32x4 v;
                        if (f < INC) v = *reinterpret_cast<const f32x4*>(xs + c * 4);
                        else         v = *reinterpret_cast<const f32x4*>(es + (f - INC));
                        sacc[c * 4 + 0] += v[0]; sacc[c * 4 + 1] += v[1];
                        sacc[c * 4 + 2] += v[2]; sacc[c * 4 + 3] += v[3];
                    }
                }
            }
            float inv = (cnt > 0) ? (1.0f / (float)cnt) : 0.0f;
#pragma unroll
            for (int c = 0; c < 10; c++) {
                int f = j * 40 + c * 4;
                unsigned lo = (unsigned)f2bf(sacc[c * 4 + 0] * inv) | ((unsigned)f2bf(sacc[c * 4 + 1] * inv) << 16);
                unsigned hi = (unsigned)f2bf(sacc[c * 4 + 2] * inv) | ((unsigned)f2bf(sacc[c * 4 + 3] * inv) << 16);
                unsigned* p = reinterpret_cast<unsigned*>(feat + nl * KP + f);
                p[0] = lo; p[1] = hi;
            }
        }
        __syncthreads();
        mfma_pass();
    }

    // ---------- epilogue: bias + ReLU, C/D layout col=lane&15, row=(lane>>4)*4+i ----------
    const int col = lane & 15;
    const int rq = lane >> 4;
#pragma unroll
    for (int t = 0; t < 8; t++) {
        float bv = bias[t * 16 + col];
#pragma unroll
        for (int i = 0; i < 4; i++) {
            int row = wave * 16 + rq * 4 + i;
            int n = n0 + row;
            if (n < NN) {
                float v = acc[t][i] + bv;
                out[(size_t)n * OC + t * 16 + col] = v > 0.f ? v : 0.f;
            }
        }
    }
}

extern "C" void kernel_launch(void* const* d_in, const int* in_sizes, int n_in,
                              void* d_out, int out_size, void* d_ws, size_t ws_size,
                              hipStream_t stream) {
    const float* x     = (const float*)d_in[0];
    const int*   ntype = (const int*)d_in[1];
    const int*   ei    = (const int*)d_in[2];
    const int*   et    = (const int*)d_in[3];
    const float* emb   = (const float*)d_in[4];
    const float* bases = (const float*)d_in[5];
    const float* comp  = (const float*)d_in[6];
    const float* rootw = (const float*)d_in[7];
    const float* bias  = (const float*)d_in[8];
    float* out = (float*)d_out;

    char* ws = (char*)d_ws;
    // layout (256-aligned): Wt 387072 | cnts 3.2M | cursor 4 | starts 3.2M | fillp 3.2M | slots 6.4M
    unsigned short* Wt = (unsigned short*)(ws + 0);
    int* cnts   = (int*)(ws + 387072);
    int* cursor = (int*)(ws + 3587072);
    int* starts = (int*)(ws + 3587328);
    int* fillp  = (int*)(ws + 6787328);
    int* slots  = (int*)(ws + 9987328);

    hipMemsetAsync(ws + 387072, 0, 3200004, stream);  // cnts + cursor
    k_wt    <<<756,  256, 0, stream>>>(comp, bases, rootw, Wt);
    k_count <<<6250, 256, 0, stream>>>(ei, et, cnts);
    k_starts<<<3125, 256, 0, stream>>>(cnts, starts, fillp, cursor);
    k_fill  <<<6250, 256, 0, stream>>>(ei, et, fillp, slots);
    k_mega  <<<1563, 256, 0, stream>>>(x, ntype, emb, bias, Wt, cnts, starts, slots, out);
}

// Round 2
// 682.922 us; speedup vs baseline: 1.2124x; 1.2124x over previous
//
#include <hip/hip_runtime.h>

#define NN 100000
#define NE 1600000
#define INC 128
#define TE 32
#define OC 128
#define NR 8
#define NBASES 8
#define FT 160
#define KP 168          // padded K stride (bf16 elems) for LDS tiles
#define TN 64           // nodes per mega block
#define NBKT 1563       // ceil(NN/64) dst buckets
#define NB1 782         // edge-chunk blocks (782*2048 >= NE)
#define EPB 2048
#define CAP 1536        // per-bucket edge cap (mean 1024, sigma 32 -> 16 sigma)

typedef float f32x4 __attribute__((ext_vector_type(4)));
typedef __bf16 bf16x8 __attribute__((ext_vector_type(8)));

__device__ __forceinline__ unsigned f2bf1(float f) {
    unsigned u = __float_as_uint(f);
    return (u + 0x7fffu + ((u >> 16) & 1u)) >> 16;   // RNE to bf16
}
__device__ __forceinline__ float bf2f(unsigned s) { return __uint_as_float(s << 16); }

// exclusive block scan over 256 per-thread values (Hillis-Steele in LDS)
__device__ __forceinline__ int bscan_excl(int v, int* tmp) {
    int tid = threadIdx.x;
    tmp[tid] = v; __syncthreads();
#pragma unroll
    for (int d = 1; d < 256; d <<= 1) {
        int t = (tid >= d) ? tmp[tid - d] : 0;
        __syncthreads();
        tmp[tid] += t;
        __syncthreads();
    }
    return tmp[tid] - v;
}

// ---- Wt[ridx][o][k] bf16; ridx 0..7 = comp@bases, ridx 8 = root_w ----
__global__ void k_wt(const float* __restrict__ comp, const float* __restrict__ bases,
                     const float* __restrict__ rootw, unsigned short* __restrict__ Wt) {
    int idx = blockIdx.x * 256 + threadIdx.x;
    const int tot = 9 * 128 * KP;
    if (idx >= tot) return;
    int ridx = idx / (128 * KP);
    int rem  = idx % (128 * KP);
    int o = rem / KP;
    int k = rem % KP;
    float v = 0.f;
    if (k < FT) {
        if (ridx < NR) {
#pragma unroll
            for (int b = 0; b < NBASES; b++)
                v += comp[ridx * NBASES + b] * bases[(b * FT + k) * OC + o];
        } else {
            v = rootw[k * OC + o];
        }
    }
    Wt[idx] = (unsigned short)f2bf1(v);
}

// ---- h[n][160] bf16 = concat(x[n], emb[ntype[n]]) ----
__global__ void k_h(const float* __restrict__ x, const int* __restrict__ nt,
                    const float* __restrict__ emb, unsigned short* __restrict__ h) {
    int idx = blockIdx.x * 256 + threadIdx.x;
    if (idx >= NN * 20) return;
    int n = idx / 20, c = idx % 20;
    f32x4 v0, v1;
    if (c < 16) {
        const float* p = x + (size_t)n * INC + c * 8;
        v0 = *(const f32x4*)p; v1 = *(const f32x4*)(p + 4);
    } else {
        int tt = nt[n];
        const float* p = emb + tt * TE + (c - 16) * 8;
        v0 = *(const f32x4*)p; v1 = *(const f32x4*)(p + 4);
    }
    uint4 o;
    o.x = f2bf1(v0.x) | (f2bf1(v0.y) << 16);
    o.y = f2bf1(v0.z) | (f2bf1(v0.w) << 16);
    o.z = f2bf1(v1.x) | (f2bf1(v1.y) << 16);
    o.w = f2bf1(v1.z) | (f2bf1(v1.w) << 16);
    *(uint4*)(h + (size_t)n * FT + c * 8) = o;
}

// ---- per-chunk LDS histogram over dst buckets (LDS atomics only) ----
__global__ __launch_bounds__(256) void k_hist1(const int* __restrict__ ei, int* __restrict__ ghist) {
    __shared__ int hist[NBKT];
    int tid = threadIdx.x;
    for (int j = tid; j < NBKT; j += 256) hist[j] = 0;
    __syncthreads();
    int e0 = blockIdx.x * EPB;
#pragma unroll
    for (int k = 0; k < EPB / 256; k++) {
        int e = e0 + k * 256 + tid;
        if (e < NE) atomicAdd(&hist[ei[NE + e] >> 6], 1);
    }
    __syncthreads();
    int* g = ghist + (size_t)blockIdx.x * NBKT;
    for (int j = tid; j < NBKT; j += 256) g[j] = hist[j];
}

__global__ void k_total(const int* __restrict__ ghist, int* __restrict__ total) {
    __shared__ int tmp[256];
    int j = blockIdx.x, tid = threadIdx.x, s = 0;
    for (int b = tid; b < NB1; b += 256) s += ghist[(size_t)b * NBKT + j];
    tmp[tid] = s; __syncthreads();
#pragma unroll
    for (int k = 128; k > 0; k >>= 1) { if (tid < k) tmp[tid] += tmp[tid + k]; __syncthreads(); }
    if (tid == 0) total[j] = tmp[0];
}

__global__ void k_scanTot(const int* __restrict__ total, int* __restrict__ bstart) {
    __shared__ int tmp[256];
    int tid = threadIdx.x, s = 0, i0 = tid * 7;
#pragma unroll
    for (int i = 0; i < 7; i++) { int j = i0 + i; if (j < NBKT) s += total[j]; }
    int run = bscan_excl(s, tmp);
#pragma unroll
    for (int i = 0; i < 7; i++) { int j = i0 + i; if (j < NBKT) { bstart[j] = run; run += total[j]; } }
    if (tid == 0) bstart[NBKT] = NE;
}

// rewrite ghist[b][j] -> absolute start for block b's edges of bucket j
__global__ void k_offsets(int* __restrict__ ghist, const int* __restrict__ bstart) {
    __shared__ int tmp[256];
    int j = blockIdx.x, tid = threadIdx.x, s = 0, b0 = tid * 4;
    int loc[4];
#pragma unroll
    for (int i = 0; i < 4; i++) {
        int b = b0 + i;
        loc[i] = (b < NB1) ? ghist[(size_t)b * NBKT + j] : 0;
        s += loc[i];
    }
    int run = bscan_excl(s, tmp) + bstart[j];
#pragma unroll
    for (int i = 0; i < 4; i++) {
        int b = b0 + i;
        if (b < NB1) { ghist[(size_t)b * NBKT + j] = run; run += loc[i]; }
    }
}

// scatter packed entries (src | rel<<17 | dst_local<<20) into bucket-contiguous slots
__global__ __launch_bounds__(256) void k_scatter1(const int* __restrict__ ei, const int* __restrict__ et,
                                                  const int* __restrict__ ghist, unsigned* __restrict__ slots) {
    __shared__ int cur[NBKT];
    int tid = threadIdx.x, b = blockIdx.x;
    for (int j = tid; j < NBKT; j += 256) cur[j] = ghist[(size_t)b * NBKT + j];
    __syncthreads();
    int e0 = b * EPB;
#pragma unroll
    for (int k = 0; k < EPB / 256; k++) {
        int e = e0 + k * 256 + tid;
        if (e < NE) {
            int s = ei[e], d = ei[NE + e], r = et[e];
            int pos = atomicAdd(&cur[d >> 6], 1);
            slots[pos] = (unsigned)s | ((unsigned)r << 17) | ((unsigned)(d & 63) << 20);
        }
    }
}

// per-bucket LDS counting sort by key=(dst_local*8+rel); emit exact (dst,rel) CSR
__global__ __launch_bounds__(256) void k_sort2(unsigned* __restrict__ slots, const int* __restrict__ bstart,
                                               int* __restrict__ cnts, int* __restrict__ starts) {
    __shared__ unsigned buf[CAP], buf2[CAP];
    __shared__ int hist[512], base[512], cur[512], tmp[256];
    int j = blockIdx.x, tid = threadIdx.x;
    int s0 = bstart[j];
    int n = bstart[j + 1] - s0; if (n > CAP) n = CAP;
    for (int i = tid; i < n; i += 256) buf[i] = slots[s0 + i];
    for (int k = tid; k < 512; k += 256) hist[k] = 0;
    __syncthreads();
    for (int i = tid; i < n; i += 256) atomicAdd(&hist[(buf[i] >> 17) & 0x1FF], 1);
    __syncthreads();
    int v0 = hist[2 * tid], v1 = hist[2 * tid + 1];
    int ex = bscan_excl(v0 + v1, tmp);
    base[2 * tid] = ex;      base[2 * tid + 1] = ex + v0;
    cur[2 * tid]  = ex;      cur[2 * tid + 1]  = ex + v0;
    __syncthreads();
    for (int k = tid; k < 512; k += 256) {
        int dl = k >> 3, nn = j * 64 + dl;
        if (nn < NN) { int key = nn * NR + (k & 7); cnts[key] = hist[k]; starts[key] = s0 + base[k]; }
    }
    for (int i = tid; i < n; i += 256) {
        unsigned v = buf[i];
        int p = atomicAdd(&cur[(v >> 17) & 0x1FF], 1);
        buf2[p] = v & 0x1FFFFu;
    }
    __syncthreads();
    for (int i = tid; i < n; i += 256) slots[s0 + i] = buf2[i];
}

// ---- fused: root GEMM + per-relation (mean-aggregate -> GEMM) + bias + ReLU ----
__global__ __launch_bounds__(256) void k_mega(
    const unsigned short* __restrict__ h, const float* __restrict__ bias,
    const unsigned short* __restrict__ Wt, const int* __restrict__ cnts,
    const int* __restrict__ starts, const unsigned* __restrict__ slots,
    float* __restrict__ out) {
    __shared__ unsigned short Wl[128 * KP];   // 43008 B
    __shared__ unsigned short feat[TN * KP];  // 21504 B

    const int tid = threadIdx.x;
    const int lane = tid & 63;
    const int wave = tid >> 6;
    const int n0 = blockIdx.x * TN;

    f32x4 acc[8];
#pragma unroll
    for (int t = 0; t < 8; t++) acc[t] = (f32x4){0.f, 0.f, 0.f, 0.f};

    auto stage_w = [&](int ridx) {
        const uint4* s = reinterpret_cast<const uint4*>(Wt + ridx * 128 * KP);
        uint4* d = reinterpret_cast<uint4*>(Wl);
        for (int i = tid; i < (128 * KP) / 8; i += 256) d[i] = s[i];
    };

    auto mfma_pass = [&]() {
        const unsigned short* fA = feat + (wave * 16 + (lane & 15)) * KP + ((lane >> 4) * 8);
        const unsigned short* fB = Wl + (lane & 15) * KP + ((lane >> 4) * 8);
#pragma unroll
        for (int kc = 0; kc < 5; kc++) {
            bf16x8 a = *reinterpret_cast<const bf16x8*>(fA + kc * 32);
#pragma unroll
            for (int t = 0; t < 8; t++) {
                bf16x8 b = *reinterpret_cast<const bf16x8*>(fB + t * 16 * KP + kc * 32);
                acc[t] = __builtin_amdgcn_mfma_f32_16x16x32_bf16(a, b, acc[t], 0, 0, 0);
            }
        }
    };

    // ---------- root pass: feat tile straight from h ----------
    stage_w(8);
    for (int i = tid; i < TN * 20; i += 256) {
        int nl = i / 20, c = i % 20, n = n0 + nl;
        uint4 v = (uint4){0u, 0u, 0u, 0u};
        if (n < NN) v = *reinterpret_cast<const uint4*>(h + (size_t)n * FT + c * 8);
        *reinterpret_cast<uint4*>(&feat[nl * KP + c * 8]) = v;
    }
    __syncthreads();
    mfma_pass();

    // ---------- relation passes: 16 lanes per node, coalesced 64B gathers ----------
    const int g = tid >> 4, l = tid & 15;
    for (int r = 0; r < NR; r++) {
        __syncthreads();          // previous mfma done with feat/Wl
        stage_w(r);
#pragma unroll
        for (int q = 0; q < 4; q++) {
            int nl = q * 16 + g, n = n0 + nl;
            float sa[10];
#pragma unroll
            for (int i = 0; i < 10; i++) sa[i] = 0.f;
            int cnt = 0, st = 0;
            if (n < NN) { int key = n * NR + r; cnt = cnts[key]; st = starts[key]; }
            for (int e = 0; e < cnt; e++) {
                int src = (int)slots[st + e];
                const unsigned* hp = reinterpret_cast<const unsigned*>(h + (size_t)src * FT) + l;
#pragma unroll
                for (int c = 0; c < 5; c++) {
                    unsigned v = hp[c * 16];          // 16 lanes x 4B = one 64B line
                    sa[2 * c]     += bf2f(v & 0xffffu);
                    sa[2 * c + 1] += bf2f(v >> 16);
                }
            }
            float inv = (cnt > 0) ? (1.0f / (float)cnt) : 0.f;
            unsigned* fp = reinterpret_cast<unsigned*>(&feat[nl * KP]) + l;
#pragma unroll
            for (int c = 0; c < 5; c++)
                fp[c * 16] = f2bf1(sa[2 * c] * inv) | (f2bf1(sa[2 * c + 1] * inv) << 16);
        }
        __syncthreads();
        mfma_pass();
    }

    // ---------- epilogue: bias + ReLU ----------
    const int col = lane & 15;
    const int rq = lane >> 4;
#pragma unroll
    for (int t = 0; t < 8; t++) {
        float bv = bias[t * 16 + col];
#pragma unroll
        for (int i = 0; i < 4; i++) {
            int row = wave * 16 + rq * 4 + i;
            int n = n0 + row;
            if (n < NN) {
                float v = acc[t][i] + bv;
                out[(size_t)n * OC + t * 16 + col] = v > 0.f ? v : 0.f;
            }
        }
    }
}

extern "C" void kernel_launch(void* const* d_in, const int* in_sizes, int n_in,
                              void* d_out, int out_size, void* d_ws, size_t ws_size,
                              hipStream_t stream) {
    const float* x     = (const float*)d_in[0];
    const int*   ntype = (const int*)d_in[1];
    const int*   ei    = (const int*)d_in[2];
    const int*   et    = (const int*)d_in[3];
    const float* emb   = (const float*)d_in[4];
    const float* bases = (const float*)d_in[5];
    const float* comp  = (const float*)d_in[6];
    const float* rootw = (const float*)d_in[7];
    const float* bias  = (const float*)d_in[8];
    float* out = (float*)d_out;

    char* ws = (char*)d_ws;
    // 256-aligned layout, total 50.1 MB:
    unsigned short* Wt     = (unsigned short*)(ws);              // 387,072
    unsigned short* h      = (unsigned short*)(ws + 387072);     // 32,000,000
    int*            ghist  = (int*)(ws + 32387072);              // 4,889,064
    int*            total  = (int*)(ws + 37276160);              // 6,252
    int*            bstart = (int*)(ws + 37282560);              // 6,256
    int*            cnts   = (int*)(ws + 37288960);              // 3,201,024
    int*            starts = (int*)(ws + 40489984);              // 3,201,024
    unsigned*       slots  = (unsigned*)(ws + 43691008);         // 6,400,000

    k_wt      <<<756,   256, 0, stream>>>(comp, bases, rootw, Wt);
    k_h       <<<7813,  256, 0, stream>>>(x, ntype, emb, h);
    k_hist1   <<<NB1,   256, 0, stream>>>(ei, ghist);
    k_total   <<<NBKT,  256, 0, stream>>>(ghist, total);
    k_scanTot <<<1,     256, 0, stream>>>(total, bstart);
    k_offsets <<<NBKT,  256, 0, stream>>>(ghist, bstart);
    k_scatter1<<<NB1,   256, 0, stream>>>(ei, et, ghist, slots);
    k_sort2   <<<NBKT,  256, 0, stream>>>(slots, bstart, cnts, starts);
    k_mega    <<<NBKT,  256, 0, stream>>>(h, bias, Wt, cnts, starts, slots, out);
}

// Round 4
// 373.871 us; speedup vs baseline: 2.2146x; 1.8266x over previous
//
#include <hip/hip_runtime.h>

#define NN 100000
#define NE 1600000
#define INC 128
#define TE 32
#define OC 128
#define NR 8
#define NBASES 8
#define FT 160
#define KP 168          // padded K stride (bf16 elems) for LDS feat tile
#define KW 160          // unpadded K stride for global Wt
#define TN 64           // nodes per mega block
#define NBKT 1563       // ceil(NN/64) dst buckets
#define NB1 782         // edge-chunk blocks (782*2048 >= NE)
#define EPB 2048
#define CAP 1536        // per-bucket edge cap (mean 1024, +16 sigma)

typedef float f32x4 __attribute__((ext_vector_type(4)));
typedef __bf16 bf16x8 __attribute__((ext_vector_type(8)));

__device__ __forceinline__ unsigned f2bf1(float f) {
    unsigned u = __float_as_uint(f);
    return (u + 0x7fffu + ((u >> 16) & 1u)) >> 16;   // RNE to bf16
}
__device__ __forceinline__ float bf2f(unsigned s) { return __uint_as_float(s << 16); }

// exclusive block scan over 256 per-thread values (Hillis-Steele in LDS)
__device__ __forceinline__ int bscan_excl(int v, int* tmp) {
    int tid = threadIdx.x;
    tmp[tid] = v; __syncthreads();
#pragma unroll
    for (int d = 1; d < 256; d <<= 1) {
        int t = (tid >= d) ? tmp[tid - d] : 0;
        __syncthreads();
        tmp[tid] += t;
        __syncthreads();
    }
    return tmp[tid] - v;
}

// ---- Wt[ridx][o][k] bf16 (K unpadded); ridx 0..7 = comp@bases, ridx 8 = root_w ----
__global__ void k_wt(const float* __restrict__ comp, const float* __restrict__ bases,
                     const float* __restrict__ rootw, unsigned short* __restrict__ Wt) {
    int idx = blockIdx.x * 256 + threadIdx.x;
    const int tot = 9 * 128 * KW;
    if (idx >= tot) return;
    int ridx = idx / (128 * KW);
    int rem  = idx % (128 * KW);
    int o = rem / KW;
    int k = rem % KW;
    float v;
    if (ridx < NR) {
        v = 0.f;
#pragma unroll
        for (int b = 0; b < NBASES; b++)
            v += comp[ridx * NBASES + b] * bases[(b * FT + k) * OC + o];
    } else {
        v = rootw[k * OC + o];
    }
    Wt[idx] = (unsigned short)f2bf1(v);
}

// ---- h[n][160] bf16 = concat(x[n], emb[ntype[n]]) ----
__global__ void k_h(const float* __restrict__ x, const int* __restrict__ nt,
                    const float* __restrict__ emb, unsigned short* __restrict__ h) {
    int idx = blockIdx.x * 256 + threadIdx.x;
    if (idx >= NN * 20) return;
    int n = idx / 20, c = idx % 20;
    f32x4 v0, v1;
    if (c < 16) {
        const float* p = x + (size_t)n * INC + c * 8;
        v0 = *(const f32x4*)p; v1 = *(const f32x4*)(p + 4);
    } else {
        int tt = nt[n];
        const float* p = emb + tt * TE + (c - 16) * 8;
        v0 = *(const f32x4*)p; v1 = *(const f32x4*)(p + 4);
    }
    uint4 o;
    o.x = f2bf1(v0.x) | (f2bf1(v0.y) << 16);
    o.y = f2bf1(v0.z) | (f2bf1(v0.w) << 16);
    o.z = f2bf1(v1.x) | (f2bf1(v1.y) << 16);
    o.w = f2bf1(v1.z) | (f2bf1(v1.w) << 16);
    *(uint4*)(h + (size_t)n * FT + c * 8) = o;
}

// ---- per-chunk LDS histogram over dst buckets (LDS atomics only) ----
__global__ __launch_bounds__(256) void k_hist1(const int* __restrict__ ei, int* __restrict__ ghist) {
    __shared__ int hist[NBKT];
    int tid = threadIdx.x;
    for (int j = tid; j < NBKT; j += 256) hist[j] = 0;
    __syncthreads();
    int e0 = blockIdx.x * EPB;
#pragma unroll
    for (int k = 0; k < EPB / 256; k++) {
        int e = e0 + k * 256 + tid;
        if (e < NE) atomicAdd(&hist[ei[NE + e] >> 6], 1);
    }
    __syncthreads();
    int* g = ghist + (size_t)blockIdx.x * NBKT;
    for (int j = tid; j < NBKT; j += 256) g[j] = hist[j];
}

__global__ void k_total(const int* __restrict__ ghist, int* __restrict__ total) {
    __shared__ int tmp[256];
    int j = blockIdx.x, tid = threadIdx.x, s = 0;
    for (int b = tid; b < NB1; b += 256) s += ghist[(size_t)b * NBKT + j];
    tmp[tid] = s; __syncthreads();
#pragma unroll
    for (int k = 128; k > 0; k >>= 1) { if (tid < k) tmp[tid] += tmp[tid + k]; __syncthreads(); }
    if (tid == 0) total[j] = tmp[0];
}

__global__ void k_scanTot(const int* __restrict__ total, int* __restrict__ bstart) {
    __shared__ int tmp[256];
    int tid = threadIdx.x, s = 0, i0 = tid * 7;
#pragma unroll
    for (int i = 0; i < 7; i++) { int j = i0 + i; if (j < NBKT) s += total[j]; }
    int run = bscan_excl(s, tmp);
#pragma unroll
    for (int i = 0; i < 7; i++) { int j = i0 + i; if (j < NBKT) { bstart[j] = run; run += total[j]; } }
    if (tid == 0) bstart[NBKT] = NE;
}

// rewrite ghist[b][j] -> absolute start for block b's edges of bucket j
__global__ void k_offsets(int* __restrict__ ghist, const int* __restrict__ bstart) {
    __shared__ int tmp[256];
    int j = blockIdx.x, tid = threadIdx.x, s = 0, b0 = tid * 4;
    int loc[4];
#pragma unroll
    for (int i = 0; i < 4; i++) {
        int b = b0 + i;
        loc[i] = (b < NB1) ? ghist[(size_t)b * NBKT + j] : 0;
        s += loc[i];
    }
    int run = bscan_excl(s, tmp) + bstart[j];
#pragma unroll
    for (int i = 0; i < 4; i++) {
        int b = b0 + i;
        if (b < NB1) { ghist[(size_t)b * NBKT + j] = run; run += loc[i]; }
    }
}

// scatter packed entries (src | rel<<17 | dst_local<<20) into bucket-contiguous slots
__global__ __launch_bounds__(256) void k_scatter1(const int* __restrict__ ei, const int* __restrict__ et,
                                                  const int* __restrict__ ghist, unsigned* __restrict__ slots) {
    __shared__ int cur[NBKT];
    int tid = threadIdx.x, b = blockIdx.x;
    for (int j = tid; j < NBKT; j += 256) cur[j] = ghist[(size_t)b * NBKT + j];
    __syncthreads();
    int e0 = b * EPB;
#pragma unroll
    for (int k = 0; k < EPB / 256; k++) {
        int e = e0 + k * 256 + tid;
        if (e < NE) {
            int s = ei[e], d = ei[NE + e], r = et[e];
            int pos = atomicAdd(&cur[d >> 6], 1);
            slots[pos] = (unsigned)s | ((unsigned)r << 17) | ((unsigned)(d & 63) << 20);
        }
    }
}

// per-bucket LDS counting sort, REL-MAJOR key = rel*64 + dst_local.
// emits packed pk[bucket][512] = bucket_rel_off | cnt<<16; slots keep src + dst_local bits.
__global__ __launch_bounds__(256) void k_sort2(unsigned* __restrict__ slots, const int* __restrict__ bstart,
                                               unsigned* __restrict__ pk) {
    __shared__ unsigned buf[CAP], buf2[CAP];
    __shared__ int hist[512], base[512], cur[512], tmp[256];
    int j = blockIdx.x, tid = threadIdx.x;
    int s0 = bstart[j];
    int n = bstart[j + 1] - s0; if (n > CAP) n = CAP;
    for (int i = tid; i < n; i += 256) buf[i] = slots[s0 + i];
    for (int k = tid; k < 512; k += 256) hist[k] = 0;
    __syncthreads();
    for (int i = tid; i < n; i += 256) {
        unsigned v = buf[i];
        int key = (int)(((v >> 17) & 7u) * 64u + ((v >> 20) & 63u));
        atomicAdd(&hist[key], 1);
    }
    __syncthreads();
    int v0 = hist[2 * tid], v1 = hist[2 * tid + 1];
    int ex = bscan_excl(v0 + v1, tmp);
    base[2 * tid] = ex;      base[2 * tid + 1] = ex + v0;
    cur[2 * tid]  = ex;      cur[2 * tid + 1]  = ex + v0;
    __syncthreads();
    for (int k = tid; k < 512; k += 256)
        pk[(size_t)j * 512 + k] = (unsigned)base[k] | ((unsigned)hist[k] << 16);
    for (int i = tid; i < n; i += 256) {
        unsigned v = buf[i];
        int key = (int)(((v >> 17) & 7u) * 64u + ((v >> 20) & 63u));
        int p = atomicAdd(&cur[key], 1);
        buf2[p] = v & 0x03F1FFFFu;   // keep src (bits 0..16) + dst_local (bits 20..25)
    }
    __syncthreads();
    for (int i = tid; i < n; i += 256) slots[s0 + i] = buf2[i];
}

// ---- fused: root GEMM + per-relation (aggregate mean -> GEMM) + bias + ReLU ----
// LDS = feat 21504 + sl 6144 + pkl 2048 = 29696 B -> 4 blocks/CU with launch_bounds(256,4)
// Waves split the N (output-col) dim: wave w owns cols 32w..32w+31, all 64 rows.
__global__ __launch_bounds__(256, 4) void k_mega(
    const unsigned short* __restrict__ h, const float* __restrict__ bias,
    const unsigned short* __restrict__ Wt, const unsigned* __restrict__ pk,
    const int* __restrict__ bstart, const unsigned* __restrict__ slots,
    float* __restrict__ out) {
    __shared__ unsigned short feat[TN * KP];
    __shared__ unsigned sl[CAP];
    __shared__ unsigned pkl[512];

    const int tid = threadIdx.x;
    const int lane = tid & 63;
    const int wave = tid >> 6;
    const int j = blockIdx.x;
    const int n0 = j * TN;

    // stage slot ids + packed (off,cnt) table into LDS
    int s0 = bstart[j];
    int m = bstart[j + 1] - s0; if (m > CAP) m = CAP;
    for (int i = tid; i < m; i += 256) sl[i] = slots[s0 + i];
    for (int k = tid; k < 512; k += 256) pkl[k] = pk[(size_t)j * 512 + k];

    // root feat tile straight from h
    for (int i = tid; i < TN * 20; i += 256) {
        int nl = i / 20, c = i % 20, n = n0 + nl;
        uint4 v = (uint4){0u, 0u, 0u, 0u};
        if (n < NN) v = *reinterpret_cast<const uint4*>(h + (size_t)n * FT + c * 8);
        *reinterpret_cast<uint4*>(&feat[nl * KP + c * 8]) = v;
    }

    f32x4 acc[8];   // acc[rt*2+ct]: row-tile rt (0..3), col-tile ct (0..1)
#pragma unroll
    for (int t = 0; t < 8; t++) acc[t] = (f32x4){0.f, 0.f, 0.f, 0.f};

    auto mfma_pass = [&](int ridx) {   // A from LDS feat, B straight from global (L2-resident)
        const unsigned short* fA = feat + (lane & 15) * KP + ((lane >> 4) * 8);
        const unsigned short* gB = Wt + (size_t)ridx * 128 * KW
                                   + (wave * 32 + (lane & 15)) * KW + ((lane >> 4) * 8);
#pragma unroll
        for (int kc = 0; kc < 5; kc++) {
            bf16x8 a0 = *reinterpret_cast<const bf16x8*>(fA + 0 * 16 * KP + kc * 32);
            bf16x8 a1 = *reinterpret_cast<const bf16x8*>(fA + 1 * 16 * KP + kc * 32);
            bf16x8 a2 = *reinterpret_cast<const bf16x8*>(fA + 2 * 16 * KP + kc * 32);
            bf16x8 a3 = *reinterpret_cast<const bf16x8*>(fA + 3 * 16 * KP + kc * 32);
#pragma unroll
            for (int ct = 0; ct < 2; ct++) {
                bf16x8 b = *reinterpret_cast<const bf16x8*>(gB + ct * 16 * KW + kc * 32);
                acc[0 * 2 + ct] = __builtin_amdgcn_mfma_f32_16x16x32_bf16(a0, b, acc[0 * 2 + ct], 0, 0, 0);
                acc[1 * 2 + ct] = __builtin_amdgcn_mfma_f32_16x16x32_bf16(a1, b, acc[1 * 2 + ct], 0, 0, 0);
                acc[2 * 2 + ct] = __builtin_amdgcn_mfma_f32_16x16x32_bf16(a2, b, acc[2 * 2 + ct], 0, 0, 0);
                acc[3 * 2 + ct] = __builtin_amdgcn_mfma_f32_16x16x32_bf16(a3, b, acc[3 * 2 + ct], 0, 0, 0);
            }
        }
    };

    __syncthreads();
    mfma_pass(8);   // root

    // aggregation: 16 lanes per group, group g owns nodes 4g..4g+3; rel-major -> contiguous lists
    const int g = tid >> 4, l = tid & 15;
    const unsigned* hw = reinterpret_cast<const unsigned*>(h);
    for (int r = 0; r < NR; r++) {
        __syncthreads();   // previous mfma done reading feat
        int b0 = r * 64 + 4 * g;
        for (int q = 0; q < 4; q++) {
            unsigned p = pkl[b0 + q];
            int off = (int)(p & 0xffffu);
            int cnt = (int)(p >> 16);
            float sa[10];
#pragma unroll
            for (int i = 0; i < 10; i++) sa[i] = 0.f;
            if (cnt > 0) {
                unsigned cur[5];
                const unsigned* hp = hw + (size_t)(sl[off] & 0x1FFFFu) * 80 + l;
#pragma unroll
                for (int c = 0; c < 5; c++) cur[c] = hp[c * 16];
                for (int e = 0; e < cnt; e++) {
                    int en = (e + 1 < cnt) ? e + 1 : e;   // clamped: always valid, always initialized
                    const unsigned* hp2 = hw + (size_t)(sl[off + en] & 0x1FFFFu) * 80 + l;
                    unsigned nx[5];
#pragma unroll
                    for (int c = 0; c < 5; c++) nx[c] = hp2[c * 16];
#pragma unroll
                    for (int c = 0; c < 5; c++) {
                        sa[2 * c]     += bf2f(cur[c] & 0xffffu);
                        sa[2 * c + 1] += bf2f(cur[c] >> 16);
                        cur[c] = nx[c];
                    }
                }
            }
            float inv = (cnt > 0) ? (1.0f / (float)cnt) : 0.f;   // cnt==0 -> exact zeros
            unsigned* fp = reinterpret_cast<unsigned*>(&feat[(4 * g + q) * KP]) + l;
#pragma unroll
            for (int c = 0; c < 5; c++)
                fp[c * 16] = f2bf1(sa[2 * c] * inv) | (f2bf1(sa[2 * c + 1] * inv) << 16);
        }
        __syncthreads();
        mfma_pass(r);
    }

    // epilogue: bias + ReLU; C/D layout col=lane&15, row=(lane>>4)*4+i per 16x16 tile
    const int rq = lane >> 4;
#pragma unroll
    for (int ct = 0; ct < 2; ct++) {
        int col = wave * 32 + ct * 16 + (lane & 15);
        float bv = bias[col];
#pragma unroll
        for (int rt = 0; rt < 4; rt++) {
#pragma unroll
            for (int i = 0; i < 4; i++) {
                int n = n0 + rt * 16 + rq * 4 + i;
                if (n < NN) {
                    float v = acc[rt * 2 + ct][i] + bv;
                    out[(size_t)n * OC + col] = v > 0.f ? v : 0.f;
                }
            }
        }
    }
}

extern "C" void kernel_launch(void* const* d_in, const int* in_sizes, int n_in,
                              void* d_out, int out_size, void* d_ws, size_t ws_size,
                              hipStream_t stream) {
    const float* x     = (const float*)d_in[0];
    const int*   ntype = (const int*)d_in[1];
    const int*   ei    = (const int*)d_in[2];
    const int*   et    = (const int*)d_in[3];
    const float* emb   = (const float*)d_in[4];
    const float* bases = (const float*)d_in[5];
    const float* comp  = (const float*)d_in[6];
    const float* rootw = (const float*)d_in[7];
    const float* bias  = (const float*)d_in[8];
    float* out = (float*)d_out;

    char* ws = (char*)d_ws;
    // 256-aligned layout, ~46.9 MB total:
    unsigned short* Wt     = (unsigned short*)(ws);              // 368,640
    unsigned short* h      = (unsigned short*)(ws + 368640);     // 32,000,000
    int*            ghist  = (int*)(ws + 32368640);              // 4,889,088
    int*            total  = (int*)(ws + 37257728);              // 6,400
    int*            bstart = (int*)(ws + 37264128);              // 6,400
    unsigned*       pk     = (unsigned*)(ws + 37270528);         // 3,201,024
    unsigned*       slots  = (unsigned*)(ws + 40471552);         // 6,400,000

    k_wt      <<<720,   256, 0, stream>>>(comp, bases, rootw, Wt);
    k_h       <<<7813,  256, 0, stream>>>(x, ntype, emb, h);
    k_hist1   <<<NB1,   256, 0, stream>>>(ei, ghist);
    k_total   <<<NBKT,  256, 0, stream>>>(ghist, total);
    k_scanTot <<<1,     256, 0, stream>>>(total, bstart);
    k_offsets <<<NBKT,  256, 0, stream>>>(ghist, bstart);
    k_scatter1<<<NB1,   256, 0, stream>>>(ei, et, ghist, slots);
    k_sort2   <<<NBKT,  256, 0, stream>>>(slots, bstart, pk);
    k_mega    <<<NBKT,  256, 0, stream>>>(h, bias, Wt, pk, bstart, slots, out);
}

// Round 5
// 372.386 us; speedup vs baseline: 2.2234x; 1.0040x over previous
//
#include <hip/hip_runtime.h>

#define NN 100000
#define NE 1600000
#define INC 128
#define TE 32
#define OC 128
#define NR 8
#define NBASES 8
#define FT 160
#define KP 168          // padded K stride (bf16 elems) for LDS feat tile
#define KW 160          // unpadded K stride for global Wt
#define TN 64           // nodes per mega block
#define NBKT 1563       // ceil(NN/64) dst buckets
#define NCH 512         // edge chunks
#define EPB 3125        // edges per chunk (512*3125 = NE exactly)
#define CAP 1536        // per-bucket edge cap (mean 1024, +16 sigma)

typedef float f32x4 __attribute__((ext_vector_type(4)));
typedef __bf16 bf16x8 __attribute__((ext_vector_type(8)));

__device__ __forceinline__ unsigned f2bf1(float f) {
    unsigned u = __float_as_uint(f);
    return (u + 0x7fffu + ((u >> 16) & 1u)) >> 16;   // RNE to bf16
}

// exclusive block scan over 256 per-thread values (Hillis-Steele in LDS)
__device__ __forceinline__ int bscan_excl(int v, int* tmp) {
    int tid = threadIdx.x;
    tmp[tid] = v; __syncthreads();
#pragma unroll
    for (int d = 1; d < 256; d <<= 1) {
        int t = (tid >= d) ? tmp[tid - d] : 0;
        __syncthreads();
        tmp[tid] += t;
        __syncthreads();
    }
    return tmp[tid] - v;
}

// ---- merged: Wt[ridx][o][k] bf16 (ridx 8 = root) AND h[n][160] bf16 = concat(x, emb[type]) ----
__global__ void k_prep(const float* __restrict__ x, const int* __restrict__ nt,
                       const float* __restrict__ emb, const float* __restrict__ comp,
                       const float* __restrict__ bases, const float* __restrict__ rootw,
                       unsigned short* __restrict__ h, unsigned short* __restrict__ Wt) {
    int idx = blockIdx.x * 256 + threadIdx.x;
    if (idx < 9 * 128 * KW) {
        int ridx = idx / (128 * KW);
        int rem  = idx % (128 * KW);
        int o = rem / KW;
        int k = rem % KW;
        float v;
        if (ridx < NR) {
            v = 0.f;
#pragma unroll
            for (int b = 0; b < NBASES; b++)
                v += comp[ridx * NBASES + b] * bases[(b * FT + k) * OC + o];
        } else {
            v = rootw[k * OC + o];
        }
        Wt[idx] = (unsigned short)f2bf1(v);
    }
    if (idx < NN * 20) {
        int n = idx / 20, c = idx % 20;
        f32x4 v0, v1;
        if (c < 16) {
            const float* p = x + (size_t)n * INC + c * 8;
            v0 = *(const f32x4*)p; v1 = *(const f32x4*)(p + 4);
        } else {
            int tt = nt[n];
            const float* p = emb + tt * TE + (c - 16) * 8;
            v0 = *(const f32x4*)p; v1 = *(const f32x4*)(p + 4);
        }
        uint4 o;
        o.x = f2bf1(v0.x) | (f2bf1(v0.y) << 16);
        o.y = f2bf1(v0.z) | (f2bf1(v0.w) << 16);
        o.z = f2bf1(v1.x) | (f2bf1(v1.y) << 16);
        o.w = f2bf1(v1.z) | (f2bf1(v1.w) << 16);
        *(uint4*)(h + (size_t)n * FT + c * 8) = o;
    }
}

// ---- per-chunk LDS histogram over dst buckets; coalesced row write ----
__global__ __launch_bounds__(256) void k_hist(const int* __restrict__ ei, int* __restrict__ ghist) {
    __shared__ int hist[NBKT];
    int tid = threadIdx.x;
    for (int j = tid; j < NBKT; j += 256) hist[j] = 0;
    __syncthreads();
    int e0 = blockIdx.x * EPB;
#pragma unroll
    for (int k = 0; k < 13; k++) {
        int i = k * 256 + tid;
        if (i < EPB) atomicAdd(&hist[ei[NE + e0 + i] >> 6], 1);
    }
    __syncthreads();
    int* g = ghist + (size_t)blockIdx.x * NBKT;
    for (int j = tid; j < NBKT; j += 256) g[j] = hist[j];
}

// thread-per-j, loop-over-b: coalesced column sums
__global__ void k_total(const int* __restrict__ ghist, int* __restrict__ total) {
    int j = blockIdx.x * 256 + threadIdx.x;
    if (j >= NBKT) return;
    int s = 0;
#pragma unroll 8
    for (int b = 0; b < NCH; b++) s += ghist[(size_t)b * NBKT + j];
    total[j] = s;
}

__global__ void k_scanTot(const int* __restrict__ total, int* __restrict__ bstart) {
    __shared__ int tmp[256];
    int tid = threadIdx.x, s = 0, i0 = tid * 7;
#pragma unroll
    for (int i = 0; i < 7; i++) { int j = i0 + i; if (j < NBKT) s += total[j]; }
    int run = bscan_excl(s, tmp);
#pragma unroll
    for (int i = 0; i < 7; i++) { int j = i0 + i; if (j < NBKT) { bstart[j] = run; run += total[j]; } }
    if (tid == 0) bstart[NBKT] = NE;
}

// thread-per-j serial prefix over b: coalesced; ghist[b][j] -> absolute chunk start
__global__ void k_offsets(int* __restrict__ ghist, const int* __restrict__ bstart) {
    int j = blockIdx.x * 256 + threadIdx.x;
    if (j >= NBKT) return;
    int run = bstart[j];
#pragma unroll 4
    for (int b = 0; b < NCH; b++) {
        int v = ghist[(size_t)b * NBKT + j];
        ghist[(size_t)b * NBKT + j] = run;
        run += v;
    }
}

// scatter packed entries (src | rel<<17 | dst_local<<20) into bucket-contiguous slots
__global__ __launch_bounds__(256) void k_scatter(const int* __restrict__ ei, const int* __restrict__ et,
                                                 const int* __restrict__ ghist, unsigned* __restrict__ slots) {
    __shared__ int cur[NBKT];
    int tid = threadIdx.x, b = blockIdx.x;
    for (int j = tid; j < NBKT; j += 256) cur[j] = ghist[(size_t)b * NBKT + j];
    __syncthreads();
    int e0 = b * EPB;
#pragma unroll
    for (int k = 0; k < 13; k++) {
        int i = k * 256 + tid;
        if (i < EPB) {
            int e = e0 + i;
            int s = ei[e], d = ei[NE + e], r = et[e];
            int pos = atomicAdd(&cur[d >> 6], 1);
            slots[pos] = (unsigned)s | ((unsigned)r << 17) | ((unsigned)(d & 63) << 20);
        }
    }
}

// ---- fused: in-LDS (rel,node) sort + root GEMM + per-relation (stream-mean -> GEMM) + bias + ReLU ----
// LDS = featmem 21504 (overlaid with sort scratch) + sl 6144 + pkl 2048 = 29696 B -> 5 blocks/CU
__global__ __launch_bounds__(256, 5) void k_mega(
    const unsigned short* __restrict__ h, const float* __restrict__ bias,
    const unsigned short* __restrict__ Wt, const int* __restrict__ bstart,
    const unsigned* __restrict__ slots, float* __restrict__ out) {
    __shared__ unsigned short featmem[TN * KP];   // phase 1: sl_in|hist|tmp ; phase 2: feat tile
    __shared__ unsigned sl[CAP];
    __shared__ unsigned pkl[512];

    const int tid = threadIdx.x;
    const int lane = tid & 63;
    const int wave = tid >> 6;
    const int j = blockIdx.x;
    const int n0 = j * TN;

    unsigned* sl_in = reinterpret_cast<unsigned*>(featmem);        // CAP dwords (6144 B)
    int* hist = reinterpret_cast<int*>(featmem) + CAP;             // 512 ints
    int* tmp  = reinterpret_cast<int*>(featmem) + CAP + 512;       // 256 ints (total 9216 <= 21504)

    // ---- phase 1: stage coarse bucket + LDS counting sort by key = rel*64 + dst_local ----
    int s0 = bstart[j];
    int m = bstart[j + 1] - s0; if (m > CAP) m = CAP;
    for (int i = tid; i < m; i += 256) sl_in[i] = slots[s0 + i];
    for (int k = tid; k < 512; k += 256) hist[k] = 0;
    __syncthreads();
    for (int i = tid; i < m; i += 256) {
        unsigned v = sl_in[i];
        atomicAdd(&hist[((v >> 17) & 7u) * 64u + ((v >> 20) & 63u)], 1);
    }
    __syncthreads();
    int v0 = hist[2 * tid], v1 = hist[2 * tid + 1];
    int ex = bscan_excl(v0 + v1, tmp);                 // internal syncs cover hist reads
    pkl[2 * tid]     = (unsigned)ex | ((unsigned)v0 << 16);
    pkl[2 * tid + 1] = (unsigned)(ex + v0) | ((unsigned)v1 << 16);
    hist[2 * tid] = ex; hist[2 * tid + 1] = ex + v0;   // hist becomes scatter cursor
    __syncthreads();
    for (int i = tid; i < m; i += 256) {
        unsigned v = sl_in[i];
        int p = atomicAdd(&hist[((v >> 17) & 7u) * 64u + ((v >> 20) & 63u)], 1);
        sl[p] = v & 0x03F1FFFFu;                       // keep src (0..16) + dst_local (20..25)
    }
    __syncthreads();

    // ---- phase 2: featmem becomes the feat tile; root feat straight from h ----
    for (int i = tid; i < TN * 20; i += 256) {
        int nl = i / 20, c = i % 20, n = n0 + nl;
        uint4 v = (uint4){0u, 0u, 0u, 0u};
        if (n < NN) v = *reinterpret_cast<const uint4*>(h + (size_t)n * FT + c * 8);
        *reinterpret_cast<uint4*>(&featmem[nl * KP + c * 8]) = v;
    }

    f32x4 acc[8];   // acc[rt*2+ct]
#pragma unroll
    for (int t = 0; t < 8; t++) acc[t] = (f32x4){0.f, 0.f, 0.f, 0.f};

    auto mfma_pass = [&](int ridx) {   // A from LDS feat, B straight from global (L2-resident)
        const unsigned short* fA = featmem + (lane & 15) * KP + ((lane >> 4) * 8);
        const unsigned short* gB = Wt + (size_t)ridx * 128 * KW
                                   + (wave * 32 + (lane & 15)) * KW + ((lane >> 4) * 8);
#pragma unroll
        for (int kc = 0; kc < 5; kc++) {
            bf16x8 a0 = *reinterpret_cast<const bf16x8*>(fA + 0 * 16 * KP + kc * 32);
            bf16x8 a1 = *reinterpret_cast<const bf16x8*>(fA + 1 * 16 * KP + kc * 32);
            bf16x8 a2 = *reinterpret_cast<const bf16x8*>(fA + 2 * 16 * KP + kc * 32);
            bf16x8 a3 = *reinterpret_cast<const bf16x8*>(fA + 3 * 16 * KP + kc * 32);
#pragma unroll
            for (int ct = 0; ct < 2; ct++) {
                bf16x8 b = *reinterpret_cast<const bf16x8*>(gB + ct * 16 * KW + kc * 32);
                acc[0 * 2 + ct] = __builtin_amdgcn_mfma_f32_16x16x32_bf16(a0, b, acc[0 * 2 + ct], 0, 0, 0);
                acc[1 * 2 + ct] = __builtin_amdgcn_mfma_f32_16x16x32_bf16(a1, b, acc[1 * 2 + ct], 0, 0, 0);
                acc[2 * 2 + ct] = __builtin_amdgcn_mfma_f32_16x16x32_bf16(a2, b, acc[2 * 2 + ct], 0, 0, 0);
                acc[3 * 2 + ct] = __builtin_amdgcn_mfma_f32_16x16x32_bf16(a3, b, acc[3 * 2 + ct], 0, 0, 0);
            }
        }
    };

    __syncthreads();
    mfma_pass(8);   // root

    // ---- aggregation: group g (16 lanes) streams its 4 nodes' rel-r edges as ONE contiguous run ----
    const int g = tid >> 4, l = tid & 15;
    const unsigned* hw = reinterpret_cast<const unsigned*>(h);
    for (int r = 0; r < NR; r++) {
        __syncthreads();   // previous mfma done reading feat
        int b0 = r * 64 + 4 * g;
        unsigned pa = pkl[b0], pd = pkl[b0 + 3];
        int sbeg = (int)(pa & 0xffffu);
        int send = (int)(pd & 0xffffu) + (int)(pd >> 16);
        float sa[10];
#pragma unroll
        for (int i = 0; i < 10; i++) sa[i] = 0.f;
        float run = 0.f;
        unsigned cur5[5]; int curdl = 0;
        if (sbeg < send) {
            unsigned v = sl[sbeg];
            const unsigned* hp = hw + (size_t)(v & 0x1FFFFu) * 80 + l;
#pragma unroll
            for (int c = 0; c < 5; c++) cur5[c] = hp[c * 16];
            curdl = (int)((v >> 20) & 63u);
        }
        for (int e = sbeg; e < send; e++) {
            int en = (e + 1 < send) ? e + 1 : e;          // clamped: always valid & initialized
            unsigned vn = sl[en];
            const unsigned* hp = hw + (size_t)(vn & 0x1FFFFu) * 80 + l;
            unsigned nx[5];
#pragma unroll
            for (int c = 0; c < 5; c++) nx[c] = hp[c * 16];
            int nxdl = (int)((vn >> 20) & 63u);
#pragma unroll
            for (int c = 0; c < 5; c++) {
                sa[2 * c]     += __uint_as_float(cur5[c] << 16);
                sa[2 * c + 1] += __uint_as_float(cur5[c] & 0xFFFF0000u);
            }
            run += 1.f;
            bool fl = (e + 1 >= send) || (nxdl != curdl); // group-uniform
            if (fl) {
                float inv = 1.0f / run;
                unsigned* fp = reinterpret_cast<unsigned*>(featmem + curdl * KP) + l;
#pragma unroll
                for (int c = 0; c < 5; c++)
                    fp[c * 16] = f2bf1(sa[2 * c] * inv) | (f2bf1(sa[2 * c + 1] * inv) << 16);
#pragma unroll
                for (int i = 0; i < 10; i++) sa[i] = 0.f;
                run = 0.f;
            }
#pragma unroll
            for (int c = 0; c < 5; c++) cur5[c] = nx[c];
            curdl = nxdl;
        }
#pragma unroll
        for (int q = 0; q < 4; q++) {                     // zero rows with no rel-r edges
            if ((pkl[b0 + q] >> 16) == 0u) {
                unsigned* fp = reinterpret_cast<unsigned*>(featmem + (4 * g + q) * KP) + l;
#pragma unroll
                for (int c = 0; c < 5; c++) fp[c * 16] = 0u;
            }
        }
        __syncthreads();
        mfma_pass(r);
    }

    // ---- epilogue: bias + ReLU; C/D layout col=lane&15, row=(lane>>4)*4+i per 16x16 tile ----
    const int rq = lane >> 4;
#pragma unroll
    for (int ct = 0; ct < 2; ct++) {
        int col = wave * 32 + ct * 16 + (lane & 15);
        float bv = bias[col];
#pragma unroll
        for (int rt = 0; rt < 4; rt++) {
#pragma unroll
            for (int i = 0; i < 4; i++) {
                int n = n0 + rt * 16 + rq * 4 + i;
                if (n < NN) {
                    float v = acc[rt * 2 + ct][i] + bv;
                    out[(size_t)n * OC + col] = v > 0.f ? v : 0.f;
                }
            }
        }
    }
}

extern "C" void kernel_launch(void* const* d_in, const int* in_sizes, int n_in,
                              void* d_out, int out_size, void* d_ws, size_t ws_size,
                              hipStream_t stream) {
    const float* x     = (const float*)d_in[0];
    const int*   ntype = (const int*)d_in[1];
    const int*   ei    = (const int*)d_in[2];
    const int*   et    = (const int*)d_in[3];
    const float* emb   = (const float*)d_in[4];
    const float* bases = (const float*)d_in[5];
    const float* comp  = (const float*)d_in[6];
    const float* rootw = (const float*)d_in[7];
    const float* bias  = (const float*)d_in[8];
    float* out = (float*)d_out;

    char* ws = (char*)d_ws;
    // 256-aligned layout, ~42 MB total:
    unsigned short* Wt     = (unsigned short*)(ws);              // 368,640
    unsigned short* h      = (unsigned short*)(ws + 368640);     // 32,000,000
    int*            ghist  = (int*)(ws + 32368640);              // 3,201,024 (512 x 1563)
    int*            total  = (int*)(ws + 35569664);              // 6,400
    int*            bstart = (int*)(ws + 35576064);              // 6,400
    unsigned*       slots  = (unsigned*)(ws + 35582464);         // 6,400,000

    k_prep   <<<7813, 256, 0, stream>>>(x, ntype, emb, comp, bases, rootw, h, Wt);
    k_hist   <<<NCH,  256, 0, stream>>>(ei, ghist);
    k_total  <<<7,    256, 0, stream>>>(ghist, total);
    k_scanTot<<<1,    256, 0, stream>>>(total, bstart);
    k_offsets<<<7,    256, 0, stream>>>(ghist, bstart);
    k_scatter<<<NCH,  256, 0, stream>>>(ei, et, ghist, slots);
    k_mega   <<<NBKT, 256, 0, stream>>>(h, bias, Wt, bstart, slots, out);
}

// Round 6
// 353.200 us; speedup vs baseline: 2.3442x; 1.0543x over previous
//
#include <hip/hip_runtime.h>

#define NN 100000
#define NE 1600000
#define INC 128
#define TE 32
#define OC 128
#define NR 8
#define NBASES 8
#define FT 160
#define KP 168          // padded K stride (bf16 elems) for LDS feat tile
#define KW 160          // unpadded K stride for global Wt
#define TN 64           // nodes per mega block
#define NBKT 1563       // ceil(NN/64) dst buckets
#define NCH 128         // edge chunks
#define EPB 12500       // edges per chunk (128*12500 = NE exactly)
#define CAP 1536        // per-bucket edge cap (mean 1024, +16 sigma)

typedef float f32x4 __attribute__((ext_vector_type(4)));
typedef __bf16 bf16x8 __attribute__((ext_vector_type(8)));

__device__ __forceinline__ unsigned f2bf1(float f) {
    unsigned u = __float_as_uint(f);
    return (u + 0x7fffu + ((u >> 16) & 1u)) >> 16;   // RNE to bf16
}

// exclusive block scan over 256 per-thread values (Hillis-Steele in LDS)
__device__ __forceinline__ int bscan_excl(int v, int* tmp) {
    int tid = threadIdx.x;
    tmp[tid] = v; __syncthreads();
#pragma unroll
    for (int d = 1; d < 256; d <<= 1) {
        int t = (tid >= d) ? tmp[tid - d] : 0;
        __syncthreads();
        tmp[tid] += t;
        __syncthreads();
    }
    return tmp[tid] - v;
}

// ---- merged: chunk histograms (blocks 0..NCH-1) + Wt/h precompute (rest) ----
__global__ __launch_bounds__(256) void k_prep(
    const float* __restrict__ x, const int* __restrict__ nt,
    const float* __restrict__ emb, const float* __restrict__ comp,
    const float* __restrict__ bases, const float* __restrict__ rootw,
    const int* __restrict__ ei,
    unsigned short* __restrict__ h, unsigned short* __restrict__ Wt,
    int* __restrict__ ghist) {
    __shared__ int hist[NBKT];
    int tid = threadIdx.x;
    int b = blockIdx.x;
    if (b < NCH) {
        for (int j = tid; j < NBKT; j += 256) hist[j] = 0;
        __syncthreads();
        int e0 = b * EPB;
#pragma unroll
        for (int k = 0; k < 49; k++) {
            int i = k * 256 + tid;
            if (i < EPB) atomicAdd(&hist[ei[NE + e0 + i] >> 6], 1);
        }
        __syncthreads();
        int* g = ghist + (size_t)b * NBKT;
        for (int j = tid; j < NBKT; j += 256) g[j] = hist[j];
        return;
    }
    int idx = (b - NCH) * 256 + tid;
    if (idx < 9 * 128 * KW) {
        int ridx = idx / (128 * KW);
        int rem  = idx % (128 * KW);
        int o = rem / KW;
        int k = rem % KW;
        float v;
        if (ridx < NR) {
            v = 0.f;
#pragma unroll
            for (int bb = 0; bb < NBASES; bb++)
                v += comp[ridx * NBASES + bb] * bases[(bb * FT + k) * OC + o];
        } else {
            v = rootw[k * OC + o];
        }
        Wt[idx] = (unsigned short)f2bf1(v);
    }
    if (idx < NN * 20) {
        int n = idx / 20, c = idx % 20;
        f32x4 v0, v1;
        if (c < 16) {
            const float* p = x + (size_t)n * INC + c * 8;
            v0 = *(const f32x4*)p; v1 = *(const f32x4*)(p + 4);
        } else {
            int tt = nt[n];
            const float* p = emb + tt * TE + (c - 16) * 8;
            v0 = *(const f32x4*)p; v1 = *(const f32x4*)(p + 4);
        }
        uint4 o;
        o.x = f2bf1(v0.x) | (f2bf1(v0.y) << 16);
        o.y = f2bf1(v0.z) | (f2bf1(v0.w) << 16);
        o.z = f2bf1(v1.x) | (f2bf1(v1.y) << 16);
        o.w = f2bf1(v1.z) | (f2bf1(v1.w) << 16);
        *(uint4*)(h + (size_t)n * FT + c * 8) = o;
    }
}

// thread-per-j, loop-over-b: coalesced column sums
__global__ void k_total(const int* __restrict__ ghist, int* __restrict__ total) {
    int j = blockIdx.x * 256 + threadIdx.x;
    if (j >= NBKT) return;
    int s = 0;
#pragma unroll 8
    for (int b = 0; b < NCH; b++) s += ghist[(size_t)b * NBKT + j];
    total[j] = s;
}

__global__ void k_scanTot(const int* __restrict__ total, int* __restrict__ bstart) {
    __shared__ int tmp[256];
    int tid = threadIdx.x, s = 0, i0 = tid * 7;
#pragma unroll
    for (int i = 0; i < 7; i++) { int j = i0 + i; if (j < NBKT) s += total[j]; }
    int run = bscan_excl(s, tmp);
#pragma unroll
    for (int i = 0; i < 7; i++) { int j = i0 + i; if (j < NBKT) { bstart[j] = run; run += total[j]; } }
    if (tid == 0) bstart[NBKT] = NE;
}

// thread-per-j serial prefix over b (coalesced): ghist[b][j] -> absolute chunk start
__global__ void k_offsets(int* __restrict__ ghist, const int* __restrict__ bstart) {
    int j = blockIdx.x * 256 + threadIdx.x;
    if (j >= NBKT) return;
    int run = bstart[j];
#pragma unroll 4
    for (int b = 0; b < NCH; b++) {
        int v = ghist[(size_t)b * NBKT + j];
        ghist[(size_t)b * NBKT + j] = run;
        run += v;
    }
}

// scatter packed entries (src | rel<<17 | dst_local<<20) into bucket-contiguous slots
__global__ __launch_bounds__(256) void k_scatter(const int* __restrict__ ei, const int* __restrict__ et,
                                                 const int* __restrict__ ghist, unsigned* __restrict__ slots) {
    __shared__ int cur[NBKT];
    int tid = threadIdx.x, b = blockIdx.x;
    for (int j = tid; j < NBKT; j += 256) cur[j] = ghist[(size_t)b * NBKT + j];
    __syncthreads();
    int e0 = b * EPB;
#pragma unroll
    for (int k = 0; k < 49; k++) {
        int i = k * 256 + tid;
        if (i < EPB) {
            int e = e0 + i;
            int s = ei[e], d = ei[NE + e], r = et[e];
            int pos = atomicAdd(&cur[d >> 6], 1);
            slots[pos] = (unsigned)s | ((unsigned)r << 17) | ((unsigned)(d & 63) << 20);
        }
    }
}

// ---- fused: in-LDS (rel,node) sort + root GEMM + per-relation (batched stream-mean -> GEMM) + bias + ReLU ----
// LDS = featmem 21504 (overlaid with sort scratch) + sl 6144 + pkl 2048 = 29696 B
__global__ __launch_bounds__(256, 4) void k_mega(
    const unsigned short* __restrict__ h, const float* __restrict__ bias,
    const unsigned short* __restrict__ Wt, const int* __restrict__ bstart,
    const unsigned* __restrict__ slots, float* __restrict__ out) {
    __shared__ unsigned short featmem[TN * KP];   // phase 1: sl_in|hist|tmp ; phase 2: feat tile
    __shared__ unsigned sl[CAP];
    __shared__ unsigned pkl[512];

    const int tid = threadIdx.x;
    const int lane = tid & 63;
    const int wave = tid >> 6;
    const int j = blockIdx.x;
    const int n0 = j * TN;

    unsigned* sl_in = reinterpret_cast<unsigned*>(featmem);        // CAP dwords
    int* hist = reinterpret_cast<int*>(featmem) + CAP;             // 512 ints
    int* tmp  = reinterpret_cast<int*>(featmem) + CAP + 512;       // 256 ints

    // ---- phase 1: LDS counting sort by key = rel*64 + dst_local ----
    int s0 = bstart[j];
    int m = bstart[j + 1] - s0; if (m > CAP) m = CAP;
    for (int i = tid; i < m; i += 256) sl_in[i] = slots[s0 + i];
    for (int k = tid; k < 512; k += 256) hist[k] = 0;
    __syncthreads();
    for (int i = tid; i < m; i += 256) {
        unsigned v = sl_in[i];
        atomicAdd(&hist[((v >> 17) & 7u) * 64u + ((v >> 20) & 63u)], 1);
    }
    __syncthreads();
    int v0 = hist[2 * tid], v1 = hist[2 * tid + 1];
    int ex = bscan_excl(v0 + v1, tmp);                 // internal syncs cover hist reads
    pkl[2 * tid]     = (unsigned)ex | ((unsigned)v0 << 16);
    pkl[2 * tid + 1] = (unsigned)(ex + v0) | ((unsigned)v1 << 16);
    hist[2 * tid] = ex; hist[2 * tid + 1] = ex + v0;   // hist becomes scatter cursor
    __syncthreads();
    for (int i = tid; i < m; i += 256) {
        unsigned v = sl_in[i];
        int p = atomicAdd(&hist[((v >> 17) & 7u) * 64u + ((v >> 20) & 63u)], 1);
        sl[p] = v & 0x03F1FFFFu;                       // keep src (0..16) + dst_local (20..25)
    }
    __syncthreads();

    // ---- phase 2: featmem becomes the feat tile; root feat straight from h ----
    for (int i = tid; i < TN * 20; i += 256) {
        int nl = i / 20, c = i % 20, n = n0 + nl;
        uint4 v = (uint4){0u, 0u, 0u, 0u};
        if (n < NN) v = *reinterpret_cast<const uint4*>(h + (size_t)n * FT + c * 8);
        *reinterpret_cast<uint4*>(&featmem[nl * KP + c * 8]) = v;
    }

    f32x4 acc[8];   // acc[rt*2+ct]
#pragma unroll
    for (int t = 0; t < 8; t++) acc[t] = (f32x4){0.f, 0.f, 0.f, 0.f};

    auto mfma_pass = [&](int ridx) {   // A from LDS feat, B straight from global (L2-resident)
        const unsigned short* fA = featmem + (lane & 15) * KP + ((lane >> 4) * 8);
        const unsigned short* gB = Wt + (size_t)ridx * 128 * KW
                                   + (wave * 32 + (lane & 15)) * KW + ((lane >> 4) * 8);
#pragma unroll
        for (int kc = 0; kc < 5; kc++) {
            bf16x8 a0 = *reinterpret_cast<const bf16x8*>(fA + 0 * 16 * KP + kc * 32);
            bf16x8 a1 = *reinterpret_cast<const bf16x8*>(fA + 1 * 16 * KP + kc * 32);
            bf16x8 a2 = *reinterpret_cast<const bf16x8*>(fA + 2 * 16 * KP + kc * 32);
            bf16x8 a3 = *reinterpret_cast<const bf16x8*>(fA + 3 * 16 * KP + kc * 32);
#pragma unroll
            for (int ct = 0; ct < 2; ct++) {
                bf16x8 b = *reinterpret_cast<const bf16x8*>(gB + ct * 16 * KW + kc * 32);
                acc[0 * 2 + ct] = __builtin_amdgcn_mfma_f32_16x16x32_bf16(a0, b, acc[0 * 2 + ct], 0, 0, 0);
                acc[1 * 2 + ct] = __builtin_amdgcn_mfma_f32_16x16x32_bf16(a1, b, acc[1 * 2 + ct], 0, 0, 0);
                acc[2 * 2 + ct] = __builtin_amdgcn_mfma_f32_16x16x32_bf16(a2, b, acc[2 * 2 + ct], 0, 0, 0);
                acc[3 * 2 + ct] = __builtin_amdgcn_mfma_f32_16x16x32_bf16(a3, b, acc[3 * 2 + ct], 0, 0, 0);
            }
        }
    };

    __syncthreads();
    mfma_pass(8);   // root

    // ---- aggregation: group g (16 lanes) streams its 4 nodes' rel-r edges, BATCH-4 pipelined ----
    const int g = tid >> 4, l = tid & 15;
    const unsigned* hw = reinterpret_cast<const unsigned*>(h);
    for (int r = 0; r < NR; r++) {
        __syncthreads();   // previous mfma done reading feat
        int b0 = r * 64 + 4 * g;
        unsigned pa = pkl[b0], pd = pkl[b0 + 3];
        int sbeg = (int)(pa & 0xffffu);
        int send = (int)(pd & 0xffffu) + (int)(pd >> 16);
        float sa[10];
#pragma unroll
        for (int i = 0; i < 10; i++) sa[i] = 0.f;
        float run = 0.f;
        for (int e = sbeg; e < send; e += 4) {
            unsigned w[4][5];
            int dl[4];
            // issue all 20 loads (clamped indices: always valid) before consuming any
#pragma unroll
            for (int u = 0; u < 4; u++) {
                int eu = e + u; if (eu >= send) eu = send - 1;
                unsigned v = sl[eu];
                const unsigned* hp = hw + (size_t)(v & 0x1FFFFu) * 80 + l;
#pragma unroll
                for (int c = 0; c < 5; c++) w[u][c] = hp[c * 16];
                dl[u] = (int)((v >> 20) & 63u);
            }
#pragma unroll
            for (int u = 0; u < 4; u++) {
                if (e + u < send) {
#pragma unroll
                    for (int c = 0; c < 5; c++) {
                        sa[2 * c]     += __uint_as_float(w[u][c] << 16);
                        sa[2 * c + 1] += __uint_as_float(w[u][c] & 0xFFFF0000u);
                    }
                    run += 1.f;
                    bool last = (e + u + 1 >= send);
                    int ndl = last ? -1 : (int)((sl[e + u + 1] >> 20) & 63u);
                    if (last || ndl != dl[u]) {           // group-uniform flush
                        float inv = 1.0f / run;
                        unsigned* fp = reinterpret_cast<unsigned*>(featmem + dl[u] * KP) + l;
#pragma unroll
                        for (int c = 0; c < 5; c++)
                            fp[c * 16] = f2bf1(sa[2 * c] * inv) | (f2bf1(sa[2 * c + 1] * inv) << 16);
#pragma unroll
                        for (int i = 0; i < 10; i++) sa[i] = 0.f;
                        run = 0.f;
                    }
                }
            }
        }
#pragma unroll
        for (int q = 0; q < 4; q++) {                     // zero rows with no rel-r edges
            if ((pkl[b0 + q] >> 16) == 0u) {
                unsigned* fp = reinterpret_cast<unsigned*>(featmem + (4 * g + q) * KP) + l;
#pragma unroll
                for (int c = 0; c < 5; c++) fp[c * 16] = 0u;
            }
        }
        __syncthreads();
        mfma_pass(r);
    }

    // ---- epilogue: bias + ReLU; C/D layout col=lane&15, row=(lane>>4)*4+i per 16x16 tile ----
    const int rq = lane >> 4;
#pragma unroll
    for (int ct = 0; ct < 2; ct++) {
        int col = wave * 32 + ct * 16 + (lane & 15);
        float bv = bias[col];
#pragma unroll
        for (int rt = 0; rt < 4; rt++) {
#pragma unroll
            for (int i = 0; i < 4; i++) {
                int n = n0 + rt * 16 + rq * 4 + i;
                if (n < NN) {
                    float v = acc[rt * 2 + ct][i] + bv;
                    out[(size_t)n * OC + col] = v > 0.f ? v : 0.f;
                }
            }
        }
    }
}

extern "C" void kernel_launch(void* const* d_in, const int* in_sizes, int n_in,
                              void* d_out, int out_size, void* d_ws, size_t ws_size,
                              hipStream_t stream) {
    const float* x     = (const float*)d_in[0];
    const int*   ntype = (const int*)d_in[1];
    const int*   ei    = (const int*)d_in[2];
    const int*   et    = (const int*)d_in[3];
    const float* emb   = (const float*)d_in[4];
    const float* bases = (const float*)d_in[5];
    const float* comp  = (const float*)d_in[6];
    const float* rootw = (const float*)d_in[7];
    const float* bias  = (const float*)d_in[8];
    float* out = (float*)d_out;

    char* ws = (char*)d_ws;
    // 256-aligned layout, ~40 MB total:
    unsigned short* Wt     = (unsigned short*)(ws);              // 368,640
    unsigned short* h      = (unsigned short*)(ws + 368640);     // 32,000,000
    int*            ghist  = (int*)(ws + 32368640);              // 800,256 B (128 x 1563 ints)
    int*            total  = (int*)(ws + 33168896);              // 6,400
    int*            bstart = (int*)(ws + 33175296);              // 6,400
    unsigned*       slots  = (unsigned*)(ws + 33181696);         // 6,400,000

    k_prep   <<<NCH + 7813, 256, 0, stream>>>(x, ntype, emb, comp, bases, rootw, ei, h, Wt, ghist);
    k_total  <<<7,    256, 0, stream>>>(ghist, total);
    k_scanTot<<<1,    256, 0, stream>>>(total, bstart);
    k_offsets<<<7,    256, 0, stream>>>(ghist, bstart);
    k_scatter<<<NCH,  256, 0, stream>>>(ei, et, ghist, slots);
    k_mega   <<<NBKT, 256, 0, stream>>>(h, bias, Wt, bstart, slots, out);
}